// Round 13
// baseline (313.312 us; speedup 1.0000x reference)
//
#include <hip/hip_runtime.h>

#define Hh 64
#define Ww 64
#define Cc 512
#define Bb 16
#define NTOK (1 + Hh * Ww)   // 4097
#define TW 4                 // output pixels per thread along w
#define TH 4                 // output pixels per thread along h

typedef float v2f __attribute__((ext_vector_type(2)));

// ---------------------------------------------------------------------------
// Prep kernel (unchanged): combine w7 + padded w5 + padded w3 + identity into
// one effective 7x7 kernel per channel, stored TRANSPOSED [tap][channel].
// Combine biases, copy cls tokens through.
// ---------------------------------------------------------------------------
__global__ void ppeg_prep(const float* __restrict__ w7, const float* __restrict__ b7,
                          const float* __restrict__ w5, const float* __restrict__ b5,
                          const float* __restrict__ w3, const float* __restrict__ b3,
                          const float* __restrict__ x, float* __restrict__ wt,
                          float* __restrict__ beff, float* __restrict__ out) {
    int idx = blockIdx.x * blockDim.x + threadIdx.x;
    if (idx < Cc * 49) {
        int c = idx / 49, t = idx % 49;
        int r = t / 7, s = t % 7;
        float v = w7[idx];
        if (r >= 1 && r <= 5 && s >= 1 && s <= 5) v += w5[c * 25 + (r - 1) * 5 + (s - 1)];
        if (r >= 2 && r <= 4 && s >= 2 && s <= 4) v += w3[c * 9 + (r - 2) * 3 + (s - 2)];
        if (t == 24) v += 1.0f;               // identity (center tap)
        wt[t * Cc + c] = v;                   // transposed store
    }
    if (idx < Cc) beff[idx] = b7[idx] + b5[idx] + b3[idx];
    if (idx < Bb * Cc) {
        int b = idx / Cc, c = idx % Cc;
        size_t o = (size_t)b * NTOK * Cc + c;
        out[o] = x[o];                        // cls token pass-through
    }
}

// ---------------------------------------------------------------------------
// Conv kernel v14 = v13 geometry with ALL 49 TAPS IN REGISTERS. No LDS,
// no __syncthreads.
//
// R12 re-audit: v13 (VGPR 44, occupancy 45%, live set fits) still shows the
// session-invariant VALUBusy 26% -> register-fit theory dead. FETCH 77 MB
// (L3-retained) and still slow -> wall is NOT HBM; it's CU-side latency.
// The remaining suspect with un-falsified evidence: the inner loop's
// DEPENDENT LDS TAP READS (up to 28 ds_read_b64 per row, each ~120 cy
// exposed vs 8-16 cy of math). v11's apparent falsification was
// CONFOUNDED: it removed LDS taps but also re-read windows 7x from global
// (411 MB L1-side) -- the regression is fully explained by the latter.
//
// v14 clean test: one variable vs v13. Taps = 49 v2f = 98 VGPRs, loaded
// once from the transposed wt slab (coalesced, amortized over 12.8K FMA).
// Inner loop: pure-register FMA; only the 10-load row window touches
// memory (batched under one vmcnt wait). __launch_bounds__(256,1) permits
// the ~160-reg allocation (min=1 cannot force a squeeze; R1 showed the
// heuristic grants 96+ when the live set demands it).
// GATES: VGPR>=128 (64 = allocator squeezed, void); WRITE~131MB (spill
// check). If right: VALUBusy -> 45-60%, conv -> 55-75us. If flat at ~26%:
// window-load latency is the wall -> declare local minimum with roofline.
//
// Kept (proven): v2f channel lanes, chunked XCD swizzle, nontemporal
// stores, 256-thread blocks, fp contract (v_pk_fma_f32), k-streaming
// (windows loaded once per row).
// ---------------------------------------------------------------------------
__global__ __launch_bounds__(256, 1)
void ppeg_conv(const float* __restrict__ x, const float* __restrict__ wt,
               const float* __restrict__ beff, float* __restrict__ out) {
#pragma clang fp contract(fast)
    const int tx = threadIdx.x;        // channel-pair lane 0..63
    const int ty = threadIdx.y;        // h-strip 0..3 (wave-uniform)

    // --- chunked XCD swizzle (XCD = linear id % 8, x fastest; bijective) ----
    const int L     = blockIdx.x + 64 * (blockIdx.y + 4 * blockIdx.z); // 0..4095
    const int g_lin = (L & 7) * 512 + (L >> 3);
    const int sp    = g_lin & 63;      // spatial block 0..63 within group
    const int g     = g_lin >> 6;      // 0..63 : (cblk, b) group
    const int cb    = (g & 3) * 128;
    const int b     = g >> 2;
    // ------------------------------------------------------------------------

    const int wblk  = sp & 15;         // 0..15 (w-tiles of 4)
    const int hblk  = sp >> 4;         // 0..3  (h-blocks of 16)
    const int oh0   = hblk * (TH * 4) + ty * TH;   // first of TH output rows
    const int wbase = wblk * TW;

    const int c0 = cb + 2 * tx;
    const float* xb  = x + ((size_t)b * NTOK + 1) * Cc + c0;  // pixel (0,0)
    const float* wtc = wt + c0;

    // All 49 effective taps in REGISTERS (98 VGPRs). Coalesced: per tap row
    // the wave reads 512 contiguous bytes of the transposed slab (L2-hot).
    v2f tap[49];
#pragma unroll
    for (int t = 0; t < 49; ++t)
        tap[t] = *(const v2f*)(wtc + (size_t)t * Cc);

    const v2f bias = *(const v2f*)&beff[c0];
    v2f acc[TH][TW];
#pragma unroll
    for (int o = 0; o < TH; ++o)
#pragma unroll
        for (int j = 0; j < TW; ++j) acc[o][j] = bias;

    const bool interior = (wblk != 0) && (wblk != 15);

    // Stream input rows ir = oh0-3 .. oh0+TH+2. Row k feeds output rows
    // o in [k-6, k] (tap row r = k-o). All indices static after unroll.
#pragma unroll
    for (int k = 0; k < TH + 6; ++k) {
        const int ir = oh0 + k - 3;
        if (ir >= 0 && ir < Hh) {              // wave-uniform (oh0 fixed/wave)
            const float* xrow = xb + (size_t)ir * (Ww * Cc);
            v2f v[TW + 6];
            if (interior) {
#pragma unroll
                for (int j = 0; j < TW + 6; ++j)
                    v[j] = *(const v2f*)(xrow + (size_t)(wbase - 3 + j) * Cc);
            } else {
#pragma unroll
                for (int j = 0; j < TW + 6; ++j) {
                    const int wc = wbase + j - 3;
                    if (wc >= 0 && wc < Ww)
                        v[j] = *(const v2f*)(xrow + (size_t)wc * Cc);
                    else {
                        v[j].x = 0.0f; v[j].y = 0.0f;
                    }
                }
            }
#pragma unroll
            for (int o = 0; o < TH; ++o) {
                if (o > k || o < k - 6) continue;   // static after unroll
                const int r = k - o;
#pragma unroll
                for (int s = 0; s < 7; ++s) {
#pragma unroll
                    for (int j = 0; j < TW; ++j)
                        acc[o][j] = tap[r * 7 + s] * v[j + s] + acc[o][j];
                }
            }
        }
    }

#pragma unroll
    for (int o = 0; o < TH; ++o) {
        float* orow = out + ((size_t)b * NTOK + 1 + (size_t)(oh0 + o) * Ww + wbase) * Cc + c0;
#pragma unroll
        for (int j = 0; j < TW; ++j)
            __builtin_nontemporal_store(acc[o][j], (v2f*)(orow + (size_t)j * Cc));
    }
}

extern "C" void kernel_launch(void* const* d_in, const int* in_sizes, int n_in,
                              void* d_out, int out_size, void* d_ws, size_t ws_size,
                              hipStream_t stream) {
    const float* x  = (const float*)d_in[0];
    const float* w7 = (const float*)d_in[1];
    const float* b7 = (const float*)d_in[2];
    const float* w5 = (const float*)d_in[3];
    const float* b5 = (const float*)d_in[4];
    const float* w3 = (const float*)d_in[5];
    const float* b3 = (const float*)d_in[6];
    float* out = (float*)d_out;

    float* wt   = (float*)d_ws;          // 49*Cc floats, transposed [tap][channel]
    float* beff = wt + 49 * Cc;          // Cc floats

    ppeg_prep<<<(Cc * 49 + 255) / 256, 256, 0, stream>>>(w7, b7, w5, b5, w3, b3,
                                                         x, wt, beff, out);

    // (4 hblk x 16 wblk) x 4 cblk x 16 b = 4096 blocks of 256 threads.
    dim3 grid(64, Cc / 128, Bb);
    dim3 block(64, 4);
    ppeg_conv<<<grid, block, 0, stream>>>(x, wt, beff, out);
}

// Round 14
// 274.946 us; speedup vs baseline: 1.1395x; 1.1395x over previous
//
#include <hip/hip_runtime.h>

#define Hh 64
#define Ww 64
#define Cc 512
#define Bb 16
#define NTOK (1 + Hh * Ww)   // 4097
#define TW 8                 // output pixels per thread along w
#define TH 4                 // output pixels per thread along h

typedef float v2f __attribute__((ext_vector_type(2)));

// ---------------------------------------------------------------------------
// Prep kernel (unchanged): combine w7 + padded w5 + padded w3 + identity into
// one effective 7x7 kernel per channel, stored TRANSPOSED [tap][channel].
// Combine biases, copy cls tokens through.
// ---------------------------------------------------------------------------
__global__ void ppeg_prep(const float* __restrict__ w7, const float* __restrict__ b7,
                          const float* __restrict__ w5, const float* __restrict__ b5,
                          const float* __restrict__ w3, const float* __restrict__ b3,
                          const float* __restrict__ x, float* __restrict__ wt,
                          float* __restrict__ beff, float* __restrict__ out) {
    int idx = blockIdx.x * blockDim.x + threadIdx.x;
    if (idx < Cc * 49) {
        int c = idx / 49, t = idx % 49;
        int r = t / 7, s = t % 7;
        float v = w7[idx];
        if (r >= 1 && r <= 5 && s >= 1 && s <= 5) v += w5[c * 25 + (r - 1) * 5 + (s - 1)];
        if (r >= 2 && r <= 4 && s >= 2 && s <= 4) v += w3[c * 9 + (r - 2) * 3 + (s - 2)];
        if (t == 24) v += 1.0f;               // identity (center tap)
        wt[t * Cc + c] = v;                   // transposed store
    }
    if (idx < Cc) beff[idx] = b7[idx] + b5[idx] + b3[idx];
    if (idx < Bb * Cc) {
        int b = idx / Cc, c = idx % Cc;
        size_t o = (size_t)b * NTOK * Cc + c;
        out[o] = x[o];                        // cls token pass-through
    }
}

// ---------------------------------------------------------------------------
// Conv kernel v15 = v10 + PINNED load/compute schedule (sched_barrier(0)).
//
// Session-closing diagnosis (R13): per-wave stall accounting across v13/v14
// shows ~100 window loads x ~600 cy SERIALLY EXPOSED per wave (lifetime
// 64K cy, VALU 4.7K). The allocator consumes each load immediately (v13:
// 44 VGPRs granted when window+acc alone need 52 -> registers reused per
// load -> dependent chain). Every prior fix left load placement to the
// scheduler, which always chose min-pressure = max-serialization.
// Attributes (R2/R3), tile shrink (v13), LDS staging (v7/v8), reg taps
// (v14) all failed to change THIS.
//
// v15: explicit vbuf[2][14] double-buffer; each iteration issues ALL of
// row k+1's 14 loads, then sched_barrier(0), then row k's ~224 pk-FMAs.
// The barrier makes sinking loads into the compute region ILLEGAL, so the
// allocator MUST keep 28 window regs + 64 acc live -> one overlapped
// latency per row instead of 14 serial ones. launch_bounds(256,1) permits
// the ~140-reg live set (v14 proved the allocator grants >64 when the
// structure demands it). Occupancy ~25% BY DESIGN; duty is the target.
// GATES: VGPR>=110 (64 = pin defeated); WRITE~131MB (spills void).
//
// Kept (proven): v2f lanes, LDS tap slab (conflict-benign, amortized),
// chunked XCD swizzle, nontemporal stores, 256-thread blocks, pk_fma.
// ---------------------------------------------------------------------------
__global__ __launch_bounds__(256, 1)
void ppeg_conv(const float* __restrict__ x, const float* __restrict__ wt,
               const float* __restrict__ beff, float* __restrict__ out) {
#pragma clang fp contract(fast)
    const int tx = threadIdx.x;        // channel-pair lane 0..63
    const int ty = threadIdx.y;        // h-strip 0..3 (wave-uniform)

    // --- chunked XCD swizzle (XCD = linear id % 8, x fastest; bijective) ----
    const int L     = blockIdx.x + 32 * (blockIdx.y + 4 * blockIdx.z); // 0..2047
    const int g_lin = (L & 7) * 256 + (L >> 3);
    const int sp    = g_lin & 31;      // spatial block 0..31 within group
    const int g     = g_lin >> 5;      // 0..63 : (cblk, b) group
    const int cb    = (g & 3) * 128;
    const int b     = g >> 2;
    // ------------------------------------------------------------------------

    const int wblk  = sp & 7;
    const int hblk  = sp >> 3;
    const int oh0   = hblk * (TH * 4) + ty * TH;   // first of TH output rows
    const int wbase = wblk * TW;

    // Stage the block's 49x128 tap slab into LDS (once), coalesced.
    __shared__ float taps[49][128];
    const int tid = ty * 64 + tx;
    for (int idx = tid; idx < 49 * 128; idx += 256) {
        taps[idx >> 7][idx & 127] = wt[(idx >> 7) * Cc + cb + (idx & 127)];
    }
    __syncthreads();

    const int c0 = cb + 2 * tx;
    const float* xb = x + ((size_t)b * NTOK + 1) * Cc + c0;  // pixel (0,0)

    const v2f bias = *(const v2f*)&beff[c0];
    v2f acc[TH][TW];
#pragma unroll
    for (int o = 0; o < TH; ++o)
#pragma unroll
        for (int j = 0; j < TW; ++j) acc[o][j] = bias;

    const bool interior = (wblk != 0) && (wblk != 7);

    v2f vbuf[2][TW + 6];               // double-buffered input row window

    auto loadrow = [&](v2f* __restrict__ v, int k) {
        const int ir = oh0 + k - 3;
        if (ir < 0 || ir >= Hh) return;            // wave-uniform
        const float* xrow = xb + (size_t)ir * (Ww * Cc);
        if (interior) {
#pragma unroll
            for (int j = 0; j < TW + 6; ++j)
                v[j] = *(const v2f*)(xrow + (size_t)(wbase - 3 + j) * Cc);
        } else {
#pragma unroll
            for (int j = 0; j < TW + 6; ++j) {
                const int wc = wbase + j - 3;
                if (wc >= 0 && wc < Ww)
                    v[j] = *(const v2f*)(xrow + (size_t)wc * Cc);
                else { v[j].x = 0.0f; v[j].y = 0.0f; }
            }
        }
    };

    loadrow(vbuf[0], 0);               // prologue: row 0 in flight
    __builtin_amdgcn_sched_barrier(0);

    // Row k feeds output rows o in [k-6, k] (tap row r = k-o).
    // Full unroll -> all vbuf indices (k&1) are compile-time constants.
#pragma unroll
    for (int k = 0; k < TH + 6; ++k) {
        // ---- load phase: row k+1's 14 loads issue back-to-back ----
        if (k + 1 < TH + 6) loadrow(vbuf[(k + 1) & 1], k + 1);
        __builtin_amdgcn_sched_barrier(0);   // loads may NOT sink below
        // ---- compute phase: row k (its loads landed last iteration) ----
        const int ir = oh0 + k - 3;
        if (ir >= 0 && ir < Hh) {                   // wave-uniform
            const v2f* v = vbuf[k & 1];
#pragma unroll
            for (int o = 0; o < TH; ++o) {
                if (o > k || o < k - 6) continue;   // static after unroll
                const int r = k - o;
#pragma unroll
                for (int s = 0; s < 7; ++s) {
                    const v2f tp = *(const v2f*)&taps[r * 7 + s][2 * tx];
#pragma unroll
                    for (int j = 0; j < TW; ++j)
                        acc[o][j] = tp * v[j + s] + acc[o][j];   // v_pk_fma_f32
                }
            }
        }
        __builtin_amdgcn_sched_barrier(0);   // compute may not hoist above next loads
    }

#pragma unroll
    for (int o = 0; o < TH; ++o) {
        float* orow = out + ((size_t)b * NTOK + 1 + (size_t)(oh0 + o) * Ww + wbase) * Cc + c0;
#pragma unroll
        for (int j = 0; j < TW; ++j)
            __builtin_nontemporal_store(acc[o][j], (v2f*)(orow + (size_t)j * Cc));
    }
}

extern "C" void kernel_launch(void* const* d_in, const int* in_sizes, int n_in,
                              void* d_out, int out_size, void* d_ws, size_t ws_size,
                              hipStream_t stream) {
    const float* x  = (const float*)d_in[0];
    const float* w7 = (const float*)d_in[1];
    const float* b7 = (const float*)d_in[2];
    const float* w5 = (const float*)d_in[3];
    const float* b5 = (const float*)d_in[4];
    const float* w3 = (const float*)d_in[5];
    const float* b3 = (const float*)d_in[6];
    float* out = (float*)d_out;

    float* wt   = (float*)d_ws;          // 49*Cc floats, transposed [tap][channel]
    float* beff = wt + 49 * Cc;          // Cc floats

    ppeg_prep<<<(Cc * 49 + 255) / 256, 256, 0, stream>>>(w7, b7, w5, b5, w3, b3,
                                                         x, wt, beff, out);

    // (4 hblk x 8 wblk) x 4 cblk x 16 b = 2048 blocks of 256 threads.
    dim3 grid(32, Cc / 128, Bb);
    dim3 block(64, 4);
    ppeg_conv<<<grid, block, 0, stream>>>(x, wt, beff, out);
}

// Round 15
// 274.121 us; speedup vs baseline: 1.1430x; 1.0030x over previous
//
#include <hip/hip_runtime.h>

#define Hh 64
#define Ww 64
#define Cc 512
#define Bb 16
#define NTOK (1 + Hh * Ww)   // 4097
#define TW 8                 // output pixels per thread along w
#define TH 4                 // output pixels per thread along h

typedef float v2f __attribute__((ext_vector_type(2)));

// ---------------------------------------------------------------------------
// Prep kernel (unchanged): combine w7 + padded w5 + padded w3 + identity into
// one effective 7x7 kernel per channel, stored TRANSPOSED [tap][channel].
// Combine biases, copy cls tokens through.
// ---------------------------------------------------------------------------
__global__ void ppeg_prep(const float* __restrict__ w7, const float* __restrict__ b7,
                          const float* __restrict__ w5, const float* __restrict__ b5,
                          const float* __restrict__ w3, const float* __restrict__ b3,
                          const float* __restrict__ x, float* __restrict__ wt,
                          float* __restrict__ beff, float* __restrict__ out) {
    int idx = blockIdx.x * blockDim.x + threadIdx.x;
    if (idx < Cc * 49) {
        int c = idx / 49, t = idx % 49;
        int r = t / 7, s = t % 7;
        float v = w7[idx];
        if (r >= 1 && r <= 5 && s >= 1 && s <= 5) v += w5[c * 25 + (r - 1) * 5 + (s - 1)];
        if (r >= 2 && r <= 4 && s >= 2 && s <= 4) v += w3[c * 9 + (r - 2) * 3 + (s - 2)];
        if (t == 24) v += 1.0f;               // identity (center tap)
        wt[t * Cc + c] = v;                   // transposed store
    }
    if (idx < Cc) beff[idx] = b7[idx] + b5[idx] + b3[idx];
    if (idx < Bb * Cc) {
        int b = idx / Cc, c = idx % Cc;
        size_t o = (size_t)b * NTOK * Cc + c;
        out[o] = x[o];                        // cls token pass-through
    }
}

// ---------------------------------------------------------------------------
// Conv kernel v16 = v10 + KEEP-ALIVE BATCH FENCE on the row window.
//
// Final diagnosis (R14, exact): v6 generation math gives 8.1K cy PER ROW
// per wave (lifetime 81K cy / 10 rows) vs ~450 cy of FMA -- and 14 loads x
// ~580 cy serial = 8.1K. Every window load is serially exposed because the
// allocator (pinned at 64 regs) REUSES 2-3 data registers for the whole
// stream: load v10; vmcnt(0); use; load v10... a dependent chain by
// register reuse. v15's sched_barrier failed because it has no IR
// semantics -- LLVM sank each load into its use site before machine
// scheduling ran (VGPR 76 = window never allocated).
//
// v16: one asm volatile("" : "+v"(v0).."+v"(v13)) after the 14 loads -- an
// IR-LEVEL USE POINT of all 14 values simultaneously. Loads cannot sink
// past their use; the allocator must make the whole window co-live; the
// row's loads issue as a batch under ONE s_waitcnt. Per-row: one ~580 cy
// latency + ~850 cy busy -> ~60% duty x 2.6 resident waves -> VALU
// saturating, instead of 14 serial latencies at 5% duty.
// GATES: VGPR >= ~100 (64 = IR fence defeated, void); WRITE ~131 MB (no
// spill). If gates pass and time is flat: the latency wall stands even
// batched -> structural ceiling, write the roofline argument.
//
// Kept (proven): v2f lanes, LDS tap slab, chunked XCD swizzle, nontemporal
// stores, 256-thread blocks, fp contract (v_pk_fma_f32).
// ---------------------------------------------------------------------------
__global__ __launch_bounds__(256, 1)
void ppeg_conv(const float* __restrict__ x, const float* __restrict__ wt,
               const float* __restrict__ beff, float* __restrict__ out) {
#pragma clang fp contract(fast)
    const int tx = threadIdx.x;        // channel-pair lane 0..63
    const int ty = threadIdx.y;        // h-strip 0..3 (wave-uniform)

    // --- chunked XCD swizzle (XCD = linear id % 8, x fastest; bijective) ----
    const int L     = blockIdx.x + 32 * (blockIdx.y + 4 * blockIdx.z); // 0..2047
    const int g_lin = (L & 7) * 256 + (L >> 3);
    const int sp    = g_lin & 31;      // spatial block 0..31 within group
    const int g     = g_lin >> 5;      // 0..63 : (cblk, b) group
    const int cb    = (g & 3) * 128;
    const int b     = g >> 2;
    // ------------------------------------------------------------------------

    const int wblk  = sp & 7;
    const int hblk  = sp >> 3;
    const int oh0   = hblk * (TH * 4) + ty * TH;   // first of TH output rows
    const int wbase = wblk * TW;

    // Stage the block's 49x128 tap slab into LDS (once), coalesced.
    __shared__ float taps[49][128];
    const int tid = ty * 64 + tx;
    for (int idx = tid; idx < 49 * 128; idx += 256) {
        taps[idx >> 7][idx & 127] = wt[(idx >> 7) * Cc + cb + (idx & 127)];
    }
    __syncthreads();

    const int c0 = cb + 2 * tx;
    const float* xb = x + ((size_t)b * NTOK + 1) * Cc + c0;  // pixel (0,0)

    const v2f bias = *(const v2f*)&beff[c0];
    v2f acc[TH][TW];
#pragma unroll
    for (int o = 0; o < TH; ++o)
#pragma unroll
        for (int j = 0; j < TW; ++j) acc[o][j] = bias;

    const bool interior = (wblk != 0) && (wblk != 7);

    // Stream input rows ir = oh0-3 .. oh0+TH+2. Row k feeds output rows
    // o in [k-6, k] (tap row r = k-o). All indices static after unroll.
#pragma unroll
    for (int k = 0; k < TH + 6; ++k) {
        const int ir = oh0 + k - 3;
        if (ir >= 0 && ir < Hh) {              // wave-uniform (oh0 fixed/wave)
            const float* xrow = xb + (size_t)ir * (Ww * Cc);
            v2f v[TW + 6];
            if (interior) {
#pragma unroll
                for (int j = 0; j < TW + 6; ++j)
                    v[j] = *(const v2f*)(xrow + (size_t)(wbase - 3 + j) * Cc);
            } else {
#pragma unroll
                for (int j = 0; j < TW + 6; ++j) {
                    const int wc = wbase + j - 3;
                    if (wc >= 0 && wc < Ww)
                        v[j] = *(const v2f*)(xrow + (size_t)wc * Cc);
                    else {
                        v[j].x = 0.0f; v[j].y = 0.0f;
                    }
                }
            }
            // IR-level use point: all 14 window values simultaneously live.
            // Forces batch issue of the row's loads under ONE vmcnt wait
            // (loads cannot sink past their use; allocator must co-allocate).
            asm volatile(""
                : "+v"(v[0]), "+v"(v[1]), "+v"(v[2]),  "+v"(v[3]),
                  "+v"(v[4]), "+v"(v[5]), "+v"(v[6]),  "+v"(v[7]),
                  "+v"(v[8]), "+v"(v[9]), "+v"(v[10]), "+v"(v[11]),
                  "+v"(v[12]), "+v"(v[13]));
#pragma unroll
            for (int o = 0; o < TH; ++o) {
                if (o > k || o < k - 6) continue;   // static after unroll
                const int r = k - o;
#pragma unroll
                for (int s = 0; s < 7; ++s) {
                    const v2f tp = *(const v2f*)&taps[r * 7 + s][2 * tx];
#pragma unroll
                    for (int j = 0; j < TW; ++j)
                        acc[o][j] = tp * v[j + s] + acc[o][j];   // v_pk_fma_f32
                }
            }
        }
    }

#pragma unroll
    for (int o = 0; o < TH; ++o) {
        float* orow = out + ((size_t)b * NTOK + 1 + (size_t)(oh0 + o) * Ww + wbase) * Cc + c0;
#pragma unroll
        for (int j = 0; j < TW; ++j)
            __builtin_nontemporal_store(acc[o][j], (v2f*)(orow + (size_t)j * Cc));
    }
}

extern "C" void kernel_launch(void* const* d_in, const int* in_sizes, int n_in,
                              void* d_out, int out_size, void* d_ws, size_t ws_size,
                              hipStream_t stream) {
    const float* x  = (const float*)d_in[0];
    const float* w7 = (const float*)d_in[1];
    const float* b7 = (const float*)d_in[2];
    const float* w5 = (const float*)d_in[3];
    const float* b5 = (const float*)d_in[4];
    const float* w3 = (const float*)d_in[5];
    const float* b3 = (const float*)d_in[6];
    float* out = (float*)d_out;

    float* wt   = (float*)d_ws;          // 49*Cc floats, transposed [tap][channel]
    float* beff = wt + 49 * Cc;          // Cc floats

    ppeg_prep<<<(Cc * 49 + 255) / 256, 256, 0, stream>>>(w7, b7, w5, b5, w3, b3,
                                                         x, wt, beff, out);

    // (4 hblk x 8 wblk) x 4 cblk x 16 b = 2048 blocks of 256 threads.
    dim3 grid(32, Cc / 128, Bb);
    dim3 block(64, 4);
    ppeg_conv<<<grid, block, 0, stream>>>(x, wt, beff, out);
}

// Round 17
// 268.691 us; speedup vs baseline: 1.1661x; 1.0202x over previous
//
#include <hip/hip_runtime.h>

#define Hh 64
#define Ww 64
#define Cc 512
#define Bb 16
#define NTOK (1 + Hh * Ww)   // 4097
#define TW 8                 // output pixels per thread along w
#define TH 4                 // output pixels per thread along h

typedef float v2f __attribute__((ext_vector_type(2)));

// ---------------------------------------------------------------------------
// Prep kernel (unchanged): combine w7 + padded w5 + padded w3 + identity into
// one effective 7x7 kernel per channel, stored TRANSPOSED [tap][channel].
// Combine biases, copy cls tokens through.
// ---------------------------------------------------------------------------
__global__ void ppeg_prep(const float* __restrict__ w7, const float* __restrict__ b7,
                          const float* __restrict__ w5, const float* __restrict__ b5,
                          const float* __restrict__ w3, const float* __restrict__ b3,
                          const float* __restrict__ x, float* __restrict__ wt,
                          float* __restrict__ beff, float* __restrict__ out) {
    int idx = blockIdx.x * blockDim.x + threadIdx.x;
    if (idx < Cc * 49) {
        int c = idx / 49, t = idx % 49;
        int r = t / 7, s = t % 7;
        float v = w7[idx];
        if (r >= 1 && r <= 5 && s >= 1 && s <= 5) v += w5[c * 25 + (r - 1) * 5 + (s - 1)];
        if (r >= 2 && r <= 4 && s >= 2 && s <= 4) v += w3[c * 9 + (r - 2) * 3 + (s - 2)];
        if (t == 24) v += 1.0f;               // identity (center tap)
        wt[t * Cc + c] = v;                   // transposed store
    }
    if (idx < Cc) beff[idx] = b7[idx] + b5[idx] + b3[idx];
    if (idx < Bb * Cc) {
        int b = idx / Cc, c = idx % Cc;
        size_t o = (size_t)b * NTOK * Cc + c;
        out[o] = x[o];                        // cls token pass-through
    }
}

// ---------------------------------------------------------------------------
// Conv kernel v18 = v17 with the OFFSET-UNIT BUG FIXED (bytes, not floats).
//
// v17 failed correctness because its `offset:` immediates were float counts
// (x512) instead of bytes (x2048 per pixel). The correct per-pixel stride
// (2048 B) makes a single-base scheme impossible (window spans +-14 KB vs
// the 13-bit signed +-4 KB range), so v18 uses FOUR base pointers per row,
// each covering 4 pixels with offsets in {-4096,-2048,0,+2048}:
//   interior: B0=wbase-1 (slots 0-3), B1=wbase+3 (4-7), B2=wbase+7 (8-11),
//             B3=wbase+11 (12-13, offsets -4096/-2048)
//   wblk==0:  bases px 2/6/10 -> slots 3-13 (0-2 zeroed)
//   wblk==7:  bases px 55/59/62 -> slots 0-10 (11-13 zeroed)
// All accessed pixels within [0,63]; bases 8B-aligned; verified slot map.
//
// Theory unchanged (R14/R15 accounting): each wave serially exposes 14 x
// ~600 cy window-load latencies per row because the allocator recycles 2-3
// data regs (VGPR pinned 64; three compiler-side fixes failed silently).
// The atomic asm block forces 28 window VGPRs co-live and ONE vmcnt wait
// per row -> per-wave duty ~10% -> ~60%.
// GATES: passed=true + absmax~0.03; VGPR ~90-110; WRITE ~131 MB.
// If correct but flat at ~104us with VGPR up: batching is not the lever ->
// structural-ceiling verdict next round.
//
// Kept (proven): v2f lanes, LDS tap slab, chunked XCD swizzle, nontemporal
// stores, 256-thread blocks, fp contract (v_pk_fma_f32).
// ---------------------------------------------------------------------------
__global__ __launch_bounds__(256, 1)
void ppeg_conv(const float* __restrict__ x, const float* __restrict__ wt,
               const float* __restrict__ beff, float* __restrict__ out) {
#pragma clang fp contract(fast)
    const int tx = threadIdx.x;        // channel-pair lane 0..63
    const int ty = threadIdx.y;        // h-strip 0..3 (wave-uniform)

    // --- chunked XCD swizzle (XCD = linear id % 8, x fastest; bijective) ----
    const int L     = blockIdx.x + 32 * (blockIdx.y + 4 * blockIdx.z); // 0..2047
    const int g_lin = (L & 7) * 256 + (L >> 3);
    const int sp    = g_lin & 31;      // spatial block 0..31 within group
    const int g     = g_lin >> 5;      // 0..63 : (cblk, b) group
    const int cb    = (g & 3) * 128;
    const int b     = g >> 2;
    // ------------------------------------------------------------------------

    const int wblk  = sp & 7;
    const int hblk  = sp >> 3;
    const int oh0   = hblk * (TH * 4) + ty * TH;   // first of TH output rows
    const int wbase = wblk * TW;

    // Stage the block's 49x128 tap slab into LDS (once), coalesced.
    __shared__ float taps[49][128];
    const int tid = ty * 64 + tx;
    for (int idx = tid; idx < 49 * 128; idx += 256) {
        taps[idx >> 7][idx & 127] = wt[(idx >> 7) * Cc + cb + (idx & 127)];
    }
    __syncthreads();

    const int c0 = cb + 2 * tx;
    const float* xb = x + ((size_t)b * NTOK + 1) * Cc + c0;  // pixel (0,0)

    const v2f bias = *(const v2f*)&beff[c0];
    v2f acc[TH][TW];
#pragma unroll
    for (int o = 0; o < TH; ++o)
#pragma unroll
        for (int j = 0; j < TW; ++j) acc[o][j] = bias;

    // Stream input rows ir = oh0-3 .. oh0+TH+2. Row k feeds output rows
    // o in [k-6, k] (tap row r = k-o). All indices static after unroll.
#pragma unroll
    for (int k = 0; k < TH + 6; ++k) {
        const int ir = oh0 + k - 3;
        if (ir >= 0 && ir < Hh) {              // wave-uniform (oh0 fixed/wave)
            const float* xrow = xb + (size_t)ir * (Ww * Cc);
            v2f w[TW + 6];
            if (wblk == 0) {
                // slots 0-2 (pixels -3..-1) zero; slots 3-13 = pixels 0..10.
                const float* B0 = xrow + (size_t)2  * Cc;   // pixels 0..3
                const float* B1 = xrow + (size_t)6  * Cc;   // pixels 4..7
                const float* B2 = xrow + (size_t)10 * Cc;   // pixels 8..10
                w[0] = (v2f)(0.0f); w[1] = (v2f)(0.0f); w[2] = (v2f)(0.0f);
                asm volatile(
                    "global_load_dwordx2 %0,  %11, off offset:-4096\n\t"
                    "global_load_dwordx2 %1,  %11, off offset:-2048\n\t"
                    "global_load_dwordx2 %2,  %11, off offset:0\n\t"
                    "global_load_dwordx2 %3,  %11, off offset:2048\n\t"
                    "global_load_dwordx2 %4,  %12, off offset:-4096\n\t"
                    "global_load_dwordx2 %5,  %12, off offset:-2048\n\t"
                    "global_load_dwordx2 %6,  %12, off offset:0\n\t"
                    "global_load_dwordx2 %7,  %12, off offset:2048\n\t"
                    "global_load_dwordx2 %8,  %13, off offset:-4096\n\t"
                    "global_load_dwordx2 %9,  %13, off offset:-2048\n\t"
                    "global_load_dwordx2 %10, %13, off offset:0\n\t"
                    "s_waitcnt vmcnt(0)"
                    : "=&v"(w[3]), "=&v"(w[4]), "=&v"(w[5]), "=&v"(w[6]),
                      "=&v"(w[7]), "=&v"(w[8]), "=&v"(w[9]), "=&v"(w[10]),
                      "=&v"(w[11]), "=&v"(w[12]), "=&v"(w[13])
                    : "v"(B0), "v"(B1), "v"(B2));
            } else if (wblk == 7) {
                // slots 0-10 = pixels 53..63; slots 11-13 (64..66) zero.
                const float* B0 = xrow + (size_t)55 * Cc;   // pixels 53..56
                const float* B1 = xrow + (size_t)59 * Cc;   // pixels 57..60
                const float* B2 = xrow + (size_t)62 * Cc;   // pixels 61..63
                asm volatile(
                    "global_load_dwordx2 %0,  %11, off offset:-4096\n\t"
                    "global_load_dwordx2 %1,  %11, off offset:-2048\n\t"
                    "global_load_dwordx2 %2,  %11, off offset:0\n\t"
                    "global_load_dwordx2 %3,  %11, off offset:2048\n\t"
                    "global_load_dwordx2 %4,  %12, off offset:-4096\n\t"
                    "global_load_dwordx2 %5,  %12, off offset:-2048\n\t"
                    "global_load_dwordx2 %6,  %12, off offset:0\n\t"
                    "global_load_dwordx2 %7,  %12, off offset:2048\n\t"
                    "global_load_dwordx2 %8,  %13, off offset:-2048\n\t"
                    "global_load_dwordx2 %9,  %13, off offset:0\n\t"
                    "global_load_dwordx2 %10, %13, off offset:2048\n\t"
                    "s_waitcnt vmcnt(0)"
                    : "=&v"(w[0]), "=&v"(w[1]), "=&v"(w[2]), "=&v"(w[3]),
                      "=&v"(w[4]), "=&v"(w[5]), "=&v"(w[6]), "=&v"(w[7]),
                      "=&v"(w[8]), "=&v"(w[9]), "=&v"(w[10])
                    : "v"(B0), "v"(B1), "v"(B2));
                w[11] = (v2f)(0.0f); w[12] = (v2f)(0.0f); w[13] = (v2f)(0.0f);
            } else {
                // interior: slots 0-13 = pixels wbase-3 .. wbase+10.
                const float* B0 = xrow + (size_t)(wbase - 1)  * Cc;  // s0-3
                const float* B1 = xrow + (size_t)(wbase + 3)  * Cc;  // s4-7
                const float* B2 = xrow + (size_t)(wbase + 7)  * Cc;  // s8-11
                const float* B3 = xrow + (size_t)(wbase + 11) * Cc;  // s12-13
                asm volatile(
                    "global_load_dwordx2 %0,  %14, off offset:-4096\n\t"
                    "global_load_dwordx2 %1,  %14, off offset:-2048\n\t"
                    "global_load_dwordx2 %2,  %14, off offset:0\n\t"
                    "global_load_dwordx2 %3,  %14, off offset:2048\n\t"
                    "global_load_dwordx2 %4,  %15, off offset:-4096\n\t"
                    "global_load_dwordx2 %5,  %15, off offset:-2048\n\t"
                    "global_load_dwordx2 %6,  %15, off offset:0\n\t"
                    "global_load_dwordx2 %7,  %15, off offset:2048\n\t"
                    "global_load_dwordx2 %8,  %16, off offset:-4096\n\t"
                    "global_load_dwordx2 %9,  %16, off offset:-2048\n\t"
                    "global_load_dwordx2 %10, %16, off offset:0\n\t"
                    "global_load_dwordx2 %11, %16, off offset:2048\n\t"
                    "global_load_dwordx2 %12, %17, off offset:-4096\n\t"
                    "global_load_dwordx2 %13, %17, off offset:-2048\n\t"
                    "s_waitcnt vmcnt(0)"
                    : "=&v"(w[0]), "=&v"(w[1]), "=&v"(w[2]), "=&v"(w[3]),
                      "=&v"(w[4]), "=&v"(w[5]), "=&v"(w[6]), "=&v"(w[7]),
                      "=&v"(w[8]), "=&v"(w[9]), "=&v"(w[10]), "=&v"(w[11]),
                      "=&v"(w[12]), "=&v"(w[13])
                    : "v"(B0), "v"(B1), "v"(B2), "v"(B3));
            }
#pragma unroll
            for (int o = 0; o < TH; ++o) {
                if (o > k || o < k - 6) continue;   // static after unroll
                const int r = k - o;
#pragma unroll
                for (int s = 0; s < 7; ++s) {
                    const v2f tp = *(const v2f*)&taps[r * 7 + s][2 * tx];
#pragma unroll
                    for (int j = 0; j < TW; ++j)
                        acc[o][j] = tp * w[j + s] + acc[o][j];   // v_pk_fma_f32
                }
            }
        }
    }

#pragma unroll
    for (int o = 0; o < TH; ++o) {
        float* orow = out + ((size_t)b * NTOK + 1 + (size_t)(oh0 + o) * Ww + wbase) * Cc + c0;
#pragma unroll
        for (int j = 0; j < TW; ++j)
            __builtin_nontemporal_store(acc[o][j], (v2f*)(orow + (size_t)j * Cc));
    }
}

extern "C" void kernel_launch(void* const* d_in, const int* in_sizes, int n_in,
                              void* d_out, int out_size, void* d_ws, size_t ws_size,
                              hipStream_t stream) {
    const float* x  = (const float*)d_in[0];
    const float* w7 = (const float*)d_in[1];
    const float* b7 = (const float*)d_in[2];
    const float* w5 = (const float*)d_in[3];
    const float* b5 = (const float*)d_in[4];
    const float* w3 = (const float*)d_in[5];
    const float* b3 = (const float*)d_in[6];
    float* out = (float*)d_out;

    float* wt   = (float*)d_ws;          // 49*Cc floats, transposed [tap][channel]
    float* beff = wt + 49 * Cc;          // Cc floats

    ppeg_prep<<<(Cc * 49 + 255) / 256, 256, 0, stream>>>(w7, b7, w5, b5, w3, b3,
                                                         x, wt, beff, out);

    // (4 hblk x 8 wblk) x 4 cblk x 16 b = 2048 blocks of 256 threads.
    dim3 grid(32, Cc / 128, Bb);
    dim3 block(64, 4);
    ppeg_conv<<<grid, block, 0, stream>>>(x, wt, beff, out);
}